// Round 3
// baseline (316.296 us; speedup 1.0000x reference)
//
#include <hip/hip_runtime.h>
#include <hip/hip_bf16.h>

typedef __bf16 bf16_t;
typedef __bf16 bf16x8 __attribute__((ext_vector_type(8)));
typedef float f32x16 __attribute__((ext_vector_type(16)));

#define NV 50000            // vocab; row NV in emb table = zeros (halo/invalid tokens)

// ---- workspace layout (bytes) ----
#define OFF_EMB 0UL
#define SZ_EMB  (50001UL*320*2)          // bf16 embeddings, padded, + zero row
#define OFF_WT  (OFF_EMB + SZ_EMB)
#define SZ_WT   (128UL*1920*2)           // W^T: per gram [128 ch][Kpad] bf16, Kpad=320/640/960
#define OFF_QN  (OFF_WT + SZ_WT)
#define SZ_QN   (128UL*3*32*128*2)       // normalized q vectors bf16
#define OFF_DN  (OFF_QN + SZ_QN)
#define SZ_DN   (128UL*3*512*128*2)      // normalized d vectors bf16
#define OFF_AQ  (OFF_DN + SZ_DN)
#define SZ_AQ   (128UL*3*32*4)           // attention gates f32
#define OFF_LP  (OFF_AQ + SZ_AQ)         // lp [B][99] f32

#if __has_builtin(__builtin_amdgcn_global_load_lds)
__device__ __forceinline__ void gll16(const void* g, void* l) {
  __builtin_amdgcn_global_load_lds((const __attribute__((address_space(1))) unsigned int*)g,
                                   (__attribute__((address_space(3))) unsigned int*)l, 16, 0, 0);
}
#else
__device__ __forceinline__ void gll16(const void* g, void* l) {
  *(uint4*)l = *(const uint4*)g;   // sync fallback, same semantics at the barrier
}
#endif

// ---------------- prep: f32 emb -> padded bf16 table (+ zero row) ----------------
__global__ __launch_bounds__(256) void k_prep_emb(const float* __restrict__ emb,
                                                  bf16_t* __restrict__ out) {
  long t = (long)blockIdx.x * 256 + threadIdx.x;   // tasks: 50001 rows * 40 chunks of 8
  if (t >= 50001L * 40) return;
  int r = (int)(t / 40), c0 = (int)(t % 40) * 8;
  bf16x8 v;
#pragma unroll
  for (int j = 0; j < 8; j++) {
    int c = c0 + j;
    float f = (r < 50000 && c < 300) ? emb[(long)r * 300 + c] : 0.f;
    v[j] = (bf16_t)f;
  }
  *(bf16x8*)(out + (long)r * 320 + c0) = v;
}

// ---------------- prep: W (n,300,128) -> W^T [128][Kpad] bf16, k-contiguous ----------------
__global__ __launch_bounds__(256) void k_prep_wt(const float* __restrict__ Wu,
                                                 const float* __restrict__ Wb,
                                                 const float* __restrict__ Wt,
                                                 bf16_t* __restrict__ wt) {
  int t = blockIdx.x * 256 + threadIdx.x;   // 30720 tasks of 8 elems
  if (t >= 30720) return;
  int g, local;
  if (t < 5120)       { g = 0; local = t; }
  else if (t < 15360) { g = 1; local = t - 5120; }
  else                { g = 2; local = t - 15360; }
  int kp = 320 * (g + 1);
  int c = local / (kp >> 3), k0 = (local % (kp >> 3)) * 8;
  const float* W = (g == 0) ? Wu : (g == 1) ? Wb : Wt;
  long base = (g == 0) ? 0L : (g == 1) ? 128L * 320 : 128L * 960;
  bf16x8 v;
#pragma unroll
  for (int j = 0; j < 8; j++) {
    int k = k0 + j, n = k / 320, ks = k % 320;
    float f = (ks < 300) ? W[((long)n * 300 + ks) * 128 + c] : 0.f;
    v[j] = (bf16_t)f;
  }
  *(bf16x8*)(wt + base + (long)c * kp + k0) = v;
}

// ---------------- prep: attention gates aq[b][g][q] ----------------
__global__ __launch_bounds__(64) void k_prep_aq(const float* __restrict__ attn_tab,
                                                const int* __restrict__ qwt,
                                                const float* __restrict__ qwm,
                                                const float* wa_u, const float* ba_u,
                                                const float* wa_b, const float* ba_b,
                                                const float* wa_t, const float* ba_t,
                                                float* __restrict__ aq) {
  int b = blockIdx.x, q = threadIdx.x;
  int qc = q < 32 ? q : 31;
  float a0 = attn_tab[qwt[b * 32 + qc]];
  float a1 = __shfl_down(a0, 1);
  float a2 = __shfl_down(a0, 2);
  if (q < 32) {
    float mq = qwm[b * 32 + q];
    float u  = mq * fmaxf(wa_u[0] * a0 + ba_u[0], 0.f);
    float bb = (q < 31) ? mq * fmaxf(wa_b[0] * a0 + wa_b[1] * a1 + ba_b[0], 0.f) : 0.f;
    float tt = (q < 30) ? mq * fmaxf(wa_t[0] * a0 + wa_t[1] * a1 + wa_t[2] * a2 + ba_t[0], 0.f) : 0.f;
    aq[(b * 3 + 0) * 32 + q] = u;
    aq[(b * 3 + 1) * 32 + q] = bb;
    aq[(b * 3 + 2) * 32 + q] = tt;
  }
}

// ---------------- conv: gather + 1/2/3-gram MFMA GEMM + relu + L2-normalize -> bf16 ----------------
// 256 threads = 4 waves, M=128 positions/block, N=128 channels.
// blocks 0..511: doc, b=blk>>2, p0=(blk&3)*128, wave w owns rows w*32..+31.
// blocks 512..543: query, 4 batches/block, wave w owns batch b0+w (34-row stride, 2 NV pads).
// kk-outer/n-inner: A-chunk staged once per kk; W sub-chunks for all gram-shifts n live in wc[n].
__global__ __launch_bounds__(256, 3) void k_conv(const bf16_t* __restrict__ embb,
                                                 const bf16_t* __restrict__ wtg,
                                                 const int* __restrict__ qwt,
                                                 const int* __restrict__ dwt,
                                                 const float* __restrict__ b_uni,
                                                 const float* __restrict__ b_bi,
                                                 const float* __restrict__ b_tri,
                                                 bf16_t* __restrict__ qn,
                                                 bf16_t* __restrict__ dn) {
  __shared__ int tok[136];
  __shared__ __align__(16) char embc[12288];  // 136 rows x 64B (+pad rows to 192)
  __shared__ __align__(16) char wc[24576];    // up to 3 x (128 rows x 64B)
  const int tid = threadIdx.x;
  const int w = tid >> 6, lane = tid & 63, lr = lane & 31, l5 = lane >> 5;
  const int blk = blockIdx.x;
  const bool isq = (blk >= 512);
  int b = 0, p0 = 0, b0 = 0, rowbase;
  if (!isq) { b = blk >> 2; p0 = (blk & 3) << 7; rowbase = w * 32; }
  else      { b0 = (blk - 512) << 2; rowbase = w * 34; }

  if (tid < 136) {
    int t;
    if (!isq) { int p = p0 + tid; t = (p < 512) ? dwt[b * 512 + p] : NV; }
    else      { int bb = tid / 34, pos = tid - bb * 34; t = (pos < 32) ? qwt[(b0 + bb) * 32 + pos] : NV; }
    tok[tid] = t;
  }
  __syncthreads();

  // A staging tasks: 768 chunks (136 real rows x 4 slots + clamped pad), linear LDS dest,
  // pre-swizzled global source (slot ^ ((row>>1)&3)).
  const bf16_t* srcE[3]; char* dstE[3];
#pragma unroll
  for (int t = 0; t < 3; t++) {
    int i = tid + t * 256;
    int r = i >> 2; if (r > 135) r = 135;
    int slot = i & 3;
    srcE[t] = embb + (long)tok[r] * 320 + ((slot ^ ((r >> 1) & 3)) << 3);
    dstE[t] = embc + i * 16;
  }

#pragma unroll
  for (int g = 0; g < 3; g++) {
    const int kp = 320 * (g + 1);
    const long wbase = (g == 0) ? 0L : (g == 1) ? 128L * 320 : 128L * 960;
    const int nw = 2 * (g + 1);
    const bf16_t* srcW[6]; char* dstW[6];
#pragma unroll
    for (int j = 0; j < 6; j++) {
      if (j < nw) {
        int i2 = tid + j * 256;
        int n = i2 >> 9, c = (i2 >> 2) & 127, slot = i2 & 3;
        srcW[j] = wtg + wbase + (long)c * kp + n * 320 + ((slot ^ ((c >> 1) & 3)) << 3);
        dstW[j] = wc + i2 * 16;
      }
    }

    f32x16 acc[4];
#pragma unroll
    for (int nt = 0; nt < 4; nt++)
#pragma unroll
      for (int r2 = 0; r2 < 16; r2++) acc[nt][r2] = 0.f;

    for (int kk = 0; kk < 10; kk++) {
#pragma unroll
      for (int t = 0; t < 3; t++) gll16(srcE[t] + kk * 32, dstE[t]);
#pragma unroll
      for (int j = 0; j < 6; j++)
        if (j < nw) gll16(srcW[j] + kk * 32, dstW[j]);
      __syncthreads();

#pragma unroll
      for (int n = 0; n <= g; n++) {
        int arow = rowbase + lr + n;
        int aswz = ((arow >> 1) & 3) << 4;
        const char* ab = embc + arow * 64;
        bf16x8 a0 = *(const bf16x8*)(ab + ((l5 << 4) ^ aswz));
        bf16x8 a1 = *(const bf16x8*)(ab + ((32 + (l5 << 4)) ^ aswz));
#pragma unroll
        for (int nt = 0; nt < 4; nt++) {
          int crow = nt * 32 + lr;
          int bswz = ((crow >> 1) & 3) << 4;
          const char* bb2 = wc + n * 8192 + crow * 64;
          bf16x8 w0 = *(const bf16x8*)(bb2 + ((l5 << 4) ^ bswz));
          bf16x8 w1 = *(const bf16x8*)(bb2 + ((32 + (l5 << 4)) ^ bswz));
          acc[nt] = __builtin_amdgcn_mfma_f32_32x32x16_bf16(a0, w0, acc[nt], 0, 0, 0);
          acc[nt] = __builtin_amdgcn_mfma_f32_32x32x16_bf16(a1, w1, acc[nt], 0, 0, 0);
        }
      }
      __syncthreads();
    }

    // epilogue: bias + relu + 1e-9, L2 norm over 128 ch, scale, store bf16 (zeros for invalid pos)
    const float* bp = (g == 0) ? b_uni : (g == 1) ? b_bi : b_tri;
    float bias[4];
#pragma unroll
    for (int nt = 0; nt < 4; nt++) bias[nt] = bp[nt * 32 + lr];
#pragma unroll
    for (int nt = 0; nt < 4; nt++)
#pragma unroll
      for (int r2 = 0; r2 < 16; r2++) {
        float v = acc[nt][r2] + bias[nt];
        acc[nt][r2] = fmaxf(v, 0.f) + 1e-9f;
      }
    float scale[16];
#pragma unroll
    for (int r2 = 0; r2 < 16; r2++) {
      float s = acc[0][r2] * acc[0][r2] + acc[1][r2] * acc[1][r2] +
                acc[2][r2] * acc[2][r2] + acc[3][r2] * acc[3][r2];
      s += __shfl_xor(s, 1);  s += __shfl_xor(s, 2);  s += __shfl_xor(s, 4);
      s += __shfl_xor(s, 8);  s += __shfl_xor(s, 16);
      scale[r2] = 1.f / fmaxf(sqrtf(s), 1e-10f);
    }
    const int L = isq ? 32 : 512;
    const int lim = L - g;
#pragma unroll
    for (int r2 = 0; r2 < 16; r2++) {
      int R = (r2 & 3) + ((r2 >> 2) << 3) + (l5 << 2);
      int pos, bi_;
      if (!isq) { pos = p0 + w * 32 + R; bi_ = b; }
      else      { pos = R; bi_ = b0 + w; }
      bool valid = pos < lim;
      bf16_t* o = (isq ? qn : dn) + (((long)bi_ * 3 + g) * L + pos) * 128 + lr;
#pragma unroll
      for (int nt = 0; nt < 4; nt++) {
        float vv = valid ? acc[nt][r2] * scale[r2] : 0.f;
        o[nt * 32] = (bf16_t)vv;
      }
    }
  }
}

// ---------------- intersect: 9 pools, sim via MFMA, 11-bin soft histogram, log, gate, q-sum ----------------
__global__ __launch_bounds__(256, 4) void k_intersect(const bf16_t* __restrict__ qn,
                                                      const bf16_t* __restrict__ dn,
                                                      const float* __restrict__ aq,
                                                      const float* __restrict__ dwm,
                                                      const float* __restrict__ mu,
                                                      const float* __restrict__ sigma,
                                                      float* __restrict__ lp) {
  __shared__ __align__(16) char qs[8192];     // 32 q rows x 256B, XOR-swizzled
  __shared__ float dwm_s[512];
  __shared__ float ps_red[4][32][11];
  __shared__ float lps_s[32][11];
  const int tid = threadIdx.x;
  const int w = tid >> 6, lane = tid & 63, lr = lane & 31, l5 = lane >> 5;
  const int b = blockIdx.x, pool = blockIdx.y;
  // pool order: uu, ut, ub, bu, tu, bb, bt, tb, tt
  const int gq = (0x29640 >> (2 * pool)) & 3;
  const int gd = (0x26418 >> (2 * pool)) & 3;

  const bf16_t* qbase = qn + ((long)b * 3 + gq) * 32 * 128;
  for (int i = tid; i < 512; i += 256) {
    int q = i >> 4, j = i & 15;
    bf16x8 v = *(const bf16x8*)(qbase + q * 128 + j * 8);
    *(bf16x8*)(qs + q * 256 + ((j ^ (q & 15)) << 4)) = v;
  }
  for (int i = tid; i < 512; i += 256) dwm_s[i] = dwm[b * 512 + i];

  // k_i(s) = exp2(c2_i*s^2 + A_i*s + B_i), c2_i = -log2(e)/(2 sigma_i^2),
  // A_i = -2 c2_i mu_i, B_i = c2_i mu_i^2  — exact regroup of exp(-(s-mu)^2/(2s^2))
  float c2[11], A_[11], B_[11];
#pragma unroll
  for (int i2 = 0; i2 < 11; i2++) {
    float m = mu[i2], s = sigma[i2];
    float c = -0.72134752f / (s * s);
    c2[i2] = c;  A_[i2] = -2.f * c * m;  B_[i2] = c * m * m;
  }
  float ps[11];
#pragma unroll
  for (int i2 = 0; i2 < 11; i2++) ps[i2] = 0.f;
  __syncthreads();

  const int lim_d = 512 - gd;
  const bf16_t* dgbase = dn + ((long)b * 3 + gd) * 512 * 128;
  for (int it = 0; it < 4; it++) {
    int d0 = it * 128 + w * 32;
    f32x16 acc;
#pragma unroll
    for (int i2 = 0; i2 < 16; i2++) acc[i2] = 0.f;
    const bf16_t* dptr = dgbase + (long)(d0 + lr) * 128;
#pragma unroll
    for (int kk = 0; kk < 4; kk++) {
      bf16x8 a0 = *(const bf16x8*)(dptr + kk * 32 + l5 * 8);
      bf16x8 a1 = *(const bf16x8*)(dptr + kk * 32 + 16 + l5 * 8);
      int koff0 = kk * 64 + (l5 << 4);
      bf16x8 b0 = *(const bf16x8*)(qs + lr * 256 + (koff0 ^ ((lr & 15) << 4)));
      bf16x8 b1 = *(const bf16x8*)(qs + lr * 256 + ((koff0 + 32) ^ ((lr & 15) << 4)));
      acc = __builtin_amdgcn_mfma_f32_32x32x16_bf16(a0, b0, acc, 0, 0, 0);
      acc = __builtin_amdgcn_mfma_f32_32x32x16_bf16(a1, b1, acc, 0, 0, 0);
    }
#pragma unroll
    for (int r2 = 0; r2 < 16; r2++) {
      int dr = d0 + (r2 & 3) + ((r2 >> 2) << 3) + (l5 << 2);
      float ad = (dr < lim_d) ? dwm_s[dr] : 0.f;
      float s = acc[r2];
      float s2 = s * s;
#pragma unroll
      for (int bin = 0; bin < 11; bin++) {
        float t = fmaf(s2, c2[bin], fmaf(s, A_[bin], B_[bin]));
        ps[bin] = fmaf(exp2f(t), ad, ps[bin]);
      }
    }
  }
#pragma unroll
  for (int bin = 0; bin < 11; bin++) ps[bin] += __shfl_xor(ps[bin], 32);
  if (l5 == 0) {
#pragma unroll
    for (int bin = 0; bin < 11; bin++) ps_red[w][lr][bin] = ps[bin];
  }
  __syncthreads();
  const float* aqb = aq + ((long)b * 3 + gq) * 32;
  for (int t = tid; t < 352; t += 256) {
    int q = t / 11, bin = t - q * 11;
    float p = ps_red[0][q][bin] + ps_red[1][q][bin] + ps_red[2][q][bin] + ps_red[3][q][bin];
    lps_s[q][bin] = logf(fmaxf(p, 1e-10f)) * 0.01f * aqb[q];
  }
  __syncthreads();
  if (tid < 11) {
    float s = 0.f;
    for (int q = 0; q < 32; q++) s += lps_s[q][tid];
    lp[(long)b * 99 + pool * 11 + tid] = s;
  }
}

// ---------------- final dense + tanh ----------------
__global__ __launch_bounds__(128) void k_final(const float* __restrict__ lp,
                                               const float* __restrict__ Wd,
                                               const float* __restrict__ bd,
                                               float* __restrict__ out) {
  int b = threadIdx.x;
  float s = bd[0];
  for (int j = 0; j < 99; j++) s = fmaf(lp[b * 99 + j], Wd[j], s);
  out[b] = tanhf(s);
}

extern "C" void kernel_launch(void* const* d_in, const int* in_sizes, int n_in,
                              void* d_out, int out_size, void* d_ws, size_t ws_size,
                              hipStream_t stream) {
  const float* emb   = (const float*)d_in[0];
  const float* attn  = (const float*)d_in[1];
  const float* Wu    = (const float*)d_in[2];
  const float* bu    = (const float*)d_in[3];
  const float* Wb    = (const float*)d_in[4];
  const float* bb    = (const float*)d_in[5];
  const float* Wt    = (const float*)d_in[6];
  const float* bt    = (const float*)d_in[7];
  const float* wau   = (const float*)d_in[8];
  const float* bau   = (const float*)d_in[9];
  const float* wab   = (const float*)d_in[10];
  const float* bab   = (const float*)d_in[11];
  const float* wat   = (const float*)d_in[12];
  const float* bat   = (const float*)d_in[13];
  const float* Wd    = (const float*)d_in[14];
  const float* bd    = (const float*)d_in[15];
  const float* mu    = (const float*)d_in[16];
  const float* sigma = (const float*)d_in[17];
  const int*   qwt   = (const int*)d_in[18];
  const int*   dwt   = (const int*)d_in[19];
  const float* qwm   = (const float*)d_in[20];
  const float* dwm   = (const float*)d_in[21];

  char* ws = (char*)d_ws;
  bf16_t* embb = (bf16_t*)(ws + OFF_EMB);
  bf16_t* wtg  = (bf16_t*)(ws + OFF_WT);
  bf16_t* qn   = (bf16_t*)(ws + OFF_QN);
  bf16_t* dn   = (bf16_t*)(ws + OFF_DN);
  float*  aq   = (float*)(ws + OFF_AQ);
  float*  lp   = (float*)(ws + OFF_LP);
  float*  out  = (float*)d_out;

  hipLaunchKernelGGL(k_prep_emb, dim3(7813), dim3(256), 0, stream, emb, embb);
  hipLaunchKernelGGL(k_prep_wt,  dim3(120),  dim3(256), 0, stream, Wu, Wb, Wt, wtg);
  hipLaunchKernelGGL(k_prep_aq,  dim3(128),  dim3(64),  0, stream,
                     attn, qwt, qwm, wau, bau, wab, bab, wat, bat, aq);
  hipLaunchKernelGGL(k_conv, dim3(544), dim3(256), 0, stream,
                     embb, wtg, qwt, dwt, bu, bb, bt, qn, dn);
  hipLaunchKernelGGL(k_intersect, dim3(128, 9), dim3(256), 0, stream,
                     qn, dn, aq, dwm, mu, sigma, lp);
  hipLaunchKernelGGL(k_final, dim3(1), dim3(128), 0, stream, lp, Wd, bd, out);
}